// Round 4
// baseline (36.608 us; speedup 1.0000x reference)
//
#include <hip/hip_runtime.h>
#include <math.h>

#define FFT_N 4096
#define RH 0.70710678118654752f
#define NEG2PI_64   (-9.81747704246810387e-2f)   // -2*pi/64
#define NEG2PI_4096 (-1.53398078788564123e-3f)   // -2*pi/4096

__device__ __forceinline__ float2 cmul(float2 a, float2 b) {
    return make_float2(a.x * b.x - a.y * b.y, a.x * b.y + a.y * b.x);
}
__device__ __forceinline__ void bfly1(float2& a, float2& b) {          // w = 1
    float2 t = b;
    b = make_float2(a.x - t.x, a.y - t.y);
    a = make_float2(a.x + t.x, a.y + t.y);
}
__device__ __forceinline__ void bflyNi(float2& a, float2& b) {         // w = -i
    float2 t = make_float2(b.y, -b.x);
    b = make_float2(a.x - t.x, a.y - t.y);
    a = make_float2(a.x + t.x, a.y + t.y);
}
__device__ __forceinline__ void bflyW(float2& a, float2& b, float2 w) {
    float2 t = cmul(w, b);
    b = make_float2(a.x - t.x, a.y - t.y);
    a = make_float2(a.x + t.x, a.y + t.y);
}

// out[k] = sum_b in[b] * W8^{b*k}, W8 = exp(-2*pi*i/8). In/out natural order.
// (Impulse-verified DIT network, carried from round-3 kernel which passed.)
__device__ __forceinline__ void dft8r(float2& a0, float2& a1, float2& a2, float2& a3,
                                      float2& a4, float2& a5, float2& a6, float2& a7)
{
    float2 n0 = a0, n1 = a4, n2 = a2, n3 = a6;
    float2 n4 = a1, n5 = a5, n6 = a3, n7 = a7;
    bfly1(n0, n1); bfly1(n2, n3); bfly1(n4, n5); bfly1(n6, n7);
    bfly1(n0, n2); bflyNi(n1, n3); bfly1(n4, n6); bflyNi(n5, n7);
    const float2 w81 = make_float2(RH, -RH), w83 = make_float2(-RH, -RH);
    bfly1(n0, n4); bflyW(n1, n5, w81); bflyNi(n2, n6); bflyW(n3, n7, w83);
    a0 = n0; a1 = n1; a2 = n2; a3 = n3; a4 = n4; a5 = n5; a6 = n6; a7 = n7;
}

// Multiply by W8^Q (Q in [0,6]) with cheap constant forms.
template<int Q>
__device__ __forceinline__ float2 mul_w8(float2 z) {
    if constexpr (Q == 0) return z;
    else if constexpr (Q == 2) return make_float2(z.y, -z.x);            // * -i
    else if constexpr (Q == 4) return make_float2(-z.x, -z.y);           // * -1
    else if constexpr (Q == 6) return make_float2(-z.y, z.x);            // * +i
    else if constexpr (Q == 1) return make_float2(RH * (z.x + z.y), RH * (z.y - z.x));
    else if constexpr (Q == 3) return make_float2(RH * (z.y - z.x), -RH * (z.x + z.y));
    else /* Q == 5 */          return make_float2(-RH * (z.x + z.y), RH * (z.x - z.y));
}

// Twiddle element v[8C+B] by W64^{C*B} = W64s[(CB)&7] * W8^{CB>>3}.
template<int C, int B>
__device__ __forceinline__ void tw64(float2 (&v)[64], const float2 (&W64s)[8]) {
    constexpr int m = C * B;
    float2 t = v[8 * C + B];
    if constexpr ((m & 7) != 0) t = cmul(t, W64s[m & 7]);
    v[8 * C + B] = mul_w8<(m >> 3)>(t);
}

#define TWROW(C) tw64<C,1>(v,W64s); tw64<C,2>(v,W64s); tw64<C,3>(v,W64s); \
                 tw64<C,4>(v,W64s); tw64<C,5>(v,W64s); tw64<C,6>(v,W64s); tw64<C,7>(v,W64s);

// In-register 64-point FFT over v[n2]. Output F[k1] lands at v[8*(k1&7) + (k1>>3)].
__device__ __forceinline__ void fft64(float2 (&v)[64], const float2 (&W64s)[8]) {
    #pragma unroll
    for (int b = 0; b < 8; ++b)
        dft8r(v[b], v[b + 8], v[b + 16], v[b + 24],
              v[b + 32], v[b + 40], v[b + 48], v[b + 56]);
    TWROW(1) TWROW(2) TWROW(3) TWROW(4) TWROW(5) TWROW(6) TWROW(7)
    #pragma unroll
    for (int c = 0; c < 8; ++c)
        dft8r(v[8 * c], v[8 * c + 1], v[8 * c + 2], v[8 * c + 3],
              v[8 * c + 4], v[8 * c + 5], v[8 * c + 6], v[8 * c + 7]);
}

__global__ __launch_bounds__(64)
void fft4096_wave(const float* __restrict__ xre, const float* __restrict__ xim,
                  float* __restrict__ yre, float* __restrict__ yim)
{
    __shared__ __align__(16) float2 sd[FFT_N];   // 32 KB -> 5 blocks/CU

    const int l = threadIdx.x;                    // lane = n1
    const size_t off = (size_t)blockIdx.x * FFT_N;
    const float* xr = xre + off;
    const float* xi = xim + off;

    // ---- Load: lane l holds x[l + 64*n2], n2 = 0..63 (coalesced dwords) ----
    float2 v[64];
    #pragma unroll
    for (int n2 = 0; n2 < 64; ++n2) {
        v[n2].x = xr[l + (n2 << 6)];
        v[n2].y = xi[l + (n2 << 6)];
    }

    // ---- W64 powers (shared by both passes): W64s[s] = W64^s ----
    float2 W64s[8];
    {
        float sn, cs;
        __sincosf(NEG2PI_64, &sn, &cs);
        W64s[0] = make_float2(1.f, 0.f);
        W64s[1] = make_float2(cs, sn);
        #pragma unroll
        for (int s = 2; s < 8; ++s) W64s[s] = cmul(W64s[s - 1], W64s[1]);
    }

    // ---- Pass A: FFT-64 over n2. F[k1] at v[8*(k1&7) + (k1>>3)] ----
    fft64(v, W64s);

    // ---- Inter-pass twiddle: F[k1] *= W4096^{l*k1} = Q[k1>>3]*S[k1&7] ----
    {
        float2 S[8], Q[8];
        float sn, cs;
        __sincosf((float)l * NEG2PI_4096, &sn, &cs);
        S[0] = make_float2(1.f, 0.f);
        S[1] = make_float2(cs, sn);
        #pragma unroll
        for (int s = 2; s < 8; ++s) S[s] = cmul(S[s - 1], S[1]);
        float2 B8 = cmul(S[4], S[4]);             // A^8
        Q[0] = make_float2(1.f, 0.f);
        Q[1] = B8;
        #pragma unroll
        for (int q = 2; q < 8; ++q) Q[q] = cmul(Q[q - 1], B8);
        #pragma unroll
        for (int hi = 0; hi < 8; ++hi) {
            #pragma unroll
            for (int lo = 0; lo < 8; ++lo) {
                if (hi == 0 && lo == 0) continue;
                float2 tw = cmul(Q[hi], S[lo]);
                v[8 * lo + hi] = cmul(v[8 * lo + hi], tw);
            }
        }
    }

    // ---- Transpose via LDS (XOR-swizzled; write b64 / read b128, both bank-even) ----
    // addr(k1, n1) = k1*64 + (n1 ^ (2*(k1&31)))
    #pragma unroll
    for (int hi = 0; hi < 8; ++hi) {
        #pragma unroll
        for (int lo = 0; lo < 8; ++lo) {
            const int k1 = 8 * hi + lo;
            sd[(k1 << 6) + (l ^ ((2 * k1) & 63))] = v[8 * lo + hi];
        }
    }
    __syncthreads();
    {
        const int cm = (2 * l) & 63;
        #pragma unroll
        for (int g = 0; g < 32; ++g) {
            const float4 p = *reinterpret_cast<const float4*>(
                &sd[(l << 6) + (((2 * g) ^ cm))]);
            v[2 * g]     = make_float2(p.x, p.y);   // u[n1 = 2g]
            v[2 * g + 1] = make_float2(p.z, p.w);   // u[n1 = 2g+1]
        }
    }

    // ---- Pass B: FFT-64 over n1. Lane l now owns output bin k1 = l ----
    fft64(v, W64s);

    // ---- Store: X[l + 64*k2] = v[8*(k2&7) + (k2>>3)] (coalesced dwords) ----
    float* yr = yre + off;
    float* yi = yim + off;
    #pragma unroll
    for (int hi = 0; hi < 8; ++hi) {
        #pragma unroll
        for (int lo = 0; lo < 8; ++lo) {
            const int k2 = 8 * hi + lo;
            yr[l + (k2 << 6)] = v[8 * lo + hi].x;
            yi[l + (k2 << 6)] = v[8 * lo + hi].y;
        }
    }
}

extern "C" void kernel_launch(void* const* d_in, const int* in_sizes, int n_in,
                              void* d_out, int out_size, void* d_ws, size_t ws_size,
                              hipStream_t stream) {
    const float* xre = (const float*)d_in[0];
    const float* xim = (const float*)d_in[1];
    const int total = in_sizes[0];          // B * N
    const int rows  = total / FFT_N;        // 2048
    float* yre = (float*)d_out;
    float* yim = yre + total;
    fft4096_wave<<<dim3(rows), dim3(64), 0, stream>>>(xre, xim, yre, yim);
}

// Round 5
// 26.802 us; speedup vs baseline: 1.3659x; 1.3659x over previous
//
#include <hip/hip_runtime.h>
#include <math.h>

#define FFT_N   4096
#define THREADS 256
#define RH 0.70710678118654752f
#define C16 0.92387953251128676f     // cos(2*pi/16)
#define S16 0.38268343236508977f     // sin(2*pi/16)
#define NEG2PI_256  (-2.45436926061702597e-2f)   // -2*pi/256
#define NEG2PI_4096 (-1.53398078788564123e-3f)   // -2*pi/4096

// Output-position map of dft16: X[k] lives in v[POS(k)].
#define POS(k) ((((k) & 3) << 2) | ((k) >> 2))

__device__ __forceinline__ float2 cmul(float2 a, float2 b) {
    return make_float2(a.x * b.x - a.y * b.y, a.x * b.y + a.y * b.x);
}

// In-place DFT-4 (W4 = -i): natural in, natural out.
__device__ __forceinline__ void dft4(float2& a, float2& b, float2& c, float2& d) {
    float2 t0 = make_float2(a.x + c.x, a.y + c.y);
    float2 t1 = make_float2(a.x - c.x, a.y - c.y);
    float2 t2 = make_float2(b.x + d.x, b.y + d.y);
    float2 t3 = make_float2(b.y - d.y, d.x - b.x);   // -i * (b - d)
    a = make_float2(t0.x + t2.x, t0.y + t2.y);
    b = make_float2(t1.x + t3.x, t1.y + t3.y);
    c = make_float2(t0.x - t2.x, t0.y - t2.y);
    d = make_float2(t1.x - t3.x, t1.y - t3.y);
}

// Multiply by W16^E = exp(-2*pi*i*E/16); constant-folded forms.
template<int E>
__device__ __forceinline__ float2 mw16(float2 z) {
    if constexpr (E == 0) return z;
    else if constexpr (E == 4) return make_float2(z.y, -z.x);                    // -i
    else if constexpr (E == 2) return make_float2(RH * (z.x + z.y), RH * (z.y - z.x));
    else if constexpr (E == 6) return make_float2(RH * (z.y - z.x), -RH * (z.x + z.y));
    else if constexpr (E == 1) return cmul(z, make_float2(C16, -S16));
    else if constexpr (E == 3) return cmul(z, make_float2(S16, -C16));
    else /* E == 9 */          return cmul(z, make_float2(-C16, S16));
}

// 16-point DFT, natural input order; output X[k] at v[POS(k)].
// Structure: 4x DFT4 over hi digit, 9 constant twiddles W16^{nl*kl}, 4x DFT4 over lo digit.
__device__ __forceinline__ void dft16(float2 (&v)[16]) {
    dft4(v[0], v[4], v[8],  v[12]);
    dft4(v[1], v[5], v[9],  v[13]);
    dft4(v[2], v[6], v[10], v[14]);
    dft4(v[3], v[7], v[11], v[15]);
    v[5]  = mw16<1>(v[5]);   v[9]  = mw16<2>(v[9]);   v[13] = mw16<3>(v[13]);
    v[6]  = mw16<2>(v[6]);   v[10] = mw16<4>(v[10]);  v[14] = mw16<6>(v[14]);
    v[7]  = mw16<3>(v[7]);   v[11] = mw16<6>(v[11]);  v[15] = mw16<9>(v[15]);
    dft4(v[0],  v[1],  v[2],  v[3]);
    dft4(v[4],  v[5],  v[6],  v[7]);
    dft4(v[8],  v[9],  v[10], v[11]);
    dft4(v[12], v[13], v[14], v[15]);
}

// 4096 = 16*16*16 DIT: n = n1 + 16*n2 + 256*n3, k = k3 + 16*k2 + 256*k1.
// Stage A: DFT16 over n3 (thread t = n1+16*n2); twiddle W256^{n2*k3}.
// Stage B: DFT16 over n2 (thread t = n1+16*k3); twiddle W4096^{n1*(k3+16*k2)}.
// Stage C: DFT16 over n1 (thread t = k3+16*k2); store X[t + 256*k1].
__global__ __launch_bounds__(THREADS)
void fft4096_r16(const float* __restrict__ xre, const float* __restrict__ xim,
                 float* __restrict__ yre, float* __restrict__ yim)
{
    __shared__ float2 sd[FFT_N];   // 32 KB -> 5 blocks/CU

    const int t  = threadIdx.x;
    const int lo = t & 15;         // stage A: n1 ; stage B: n1 ; stage C: k3
    const int hi = t >> 4;         // stage A: n2 ; stage B: k3 ; stage C: k2
    const size_t off = (size_t)blockIdx.x * FFT_N;
    const float* xr = xre + off;
    const float* xi = xim + off;

    // ---- Stage A: coalesced stride-256 gather, DFT16 over n3 ----
    float2 v[16];
    #pragma unroll
    for (int n3 = 0; n3 < 16; ++n3) {
        v[n3].x = xr[t + (n3 << 8)];
        v[n3].y = xi[t + (n3 << 8)];
    }
    dft16(v);

    // Twiddle W256^{n2*k3} and write RT1: sd[t + 256*k3]  (uniform 4/pair-bank)
    {
        float sn, cs;
        __sincosf((float)hi * NEG2PI_256, &sn, &cs);
        const float2 base = make_float2(cs, sn);
        float2 P = base;
        sd[t] = v[POS(0)];
        #pragma unroll
        for (int k3 = 1; k3 < 16; ++k3) {
            sd[t + (k3 << 8)] = cmul(v[POS(k3)], P);
            P = cmul(P, base);
        }
    }
    __syncthreads();

    // RT1 read: u[n2] = sd[n1 + 16*n2 + 256*k3]  (uniform 4/pair-bank)
    #pragma unroll
    for (int n2 = 0; n2 < 16; ++n2)
        v[n2] = sd[lo + (n2 << 4) + (hi << 8)];
    __syncthreads();   // sd reused by RT2 writes

    // ---- Stage B: DFT16 over n2 ----
    dft16(v);

    // Twiddle W4096^{n1*k3} * (W256^{n1})^{k2}; write RT2 XOR-swizzled:
    // sd[(k3^n1) + 16*k2 + 256*n1]  (uniform 4/pair-bank)
    {
        float sn, cs;
        __sincosf((float)(lo * hi) * NEG2PI_4096, &sn, &cs);
        float2 P = make_float2(cs, sn);
        __sincosf((float)lo * NEG2PI_256, &sn, &cs);
        const float2 base = make_float2(cs, sn);
        const int wb = (hi ^ lo) + (lo << 8);
        #pragma unroll
        for (int k2 = 0; k2 < 16; ++k2) {
            sd[wb + (k2 << 4)] = cmul(v[POS(k2)], P);
            P = cmul(P, base);
        }
    }
    __syncthreads();

    // RT2 read: w[n1] = sd[(k3^n1) + 16*k2 + 256*n1]  (uniform 4/pair-bank)
    #pragma unroll
    for (int m = 0; m < 16; ++m)
        v[m] = sd[(lo ^ m) + (hi << 4) + (m << 8)];

    // ---- Stage C: DFT16 over n1; coalesced stride-256 scatter ----
    dft16(v);
    float* yr = yre + off;
    float* yi = yim + off;
    #pragma unroll
    for (int k1 = 0; k1 < 16; ++k1) {
        yr[t + (k1 << 8)] = v[POS(k1)].x;
        yi[t + (k1 << 8)] = v[POS(k1)].y;
    }
}

extern "C" void kernel_launch(void* const* d_in, const int* in_sizes, int n_in,
                              void* d_out, int out_size, void* d_ws, size_t ws_size,
                              hipStream_t stream) {
    const float* xre = (const float*)d_in[0];
    const float* xim = (const float*)d_in[1];
    const int total = in_sizes[0];          // B * N
    const int rows  = total / FFT_N;        // 2048
    float* yre = (float*)d_out;
    float* yim = yre + total;
    fft4096_r16<<<dim3(rows), dim3(THREADS), 0, stream>>>(xre, xim, yre, yim);
}